// Round 19
// baseline (64.748 us; speedup 1.0000x reference)
//
#include <hip/hip_runtime.h>
#include <stdint.h>

typedef unsigned short ushort_t;
typedef short short8 __attribute__((ext_vector_type(8)));
typedef float float4_ __attribute__((ext_vector_type(4)));
typedef unsigned short u16x8 __attribute__((ext_vector_type(8)));

#define INF_ 10000.0f
#define BATCH 8
#define SEQLEN 512
#define HIDDEN 1024
#define HEADS 12
#define HEAD_SIZE 64
#define NOUT 1536          // HEADS * 2 * HEAD_SIZE
#define MROWS 4096         // BATCH * SEQLEN
#define BH 96              // BATCH * HEADS
#define LOGITS_N 25165824  // (8,12,512,512)
#define MASK_N   2097152   // (8,1,512,512)

// ---- module-scope device scratch ----
__device__ __align__(16) ushort_t g_Wt[(size_t)NOUT * HIDDEN];            // 3 MB bf16
__device__ __align__(16) ushort_t g_Q[(size_t)BH * SEQLEN * HEAD_SIZE];   // 6 MB
__device__ __align__(16) ushort_t g_K[(size_t)BH * SEQLEN * HEAD_SIZE];   // 6 MB
__device__ __align__(16) float    g_tab[SEQLEN * 32 * 2];                 // 128 KB

__device__ __forceinline__ ushort_t f2bf(float f) {
    unsigned u = __builtin_bit_cast(unsigned, f);
    unsigned r = u + 0x7FFFu + ((u >> 16) & 1u);
    return (ushort_t)(r >> 16);
}

// async global->LDS 16B (LDS dest = wave-uniform base + lane*16, linear)
__device__ __forceinline__ void gload16(const ushort_t* g, ushort_t* l) {
    __builtin_amdgcn_global_load_lds(
        (const __attribute__((address_space(1))) void*)g,
        (__attribute__((address_space(3))) void*)l, 16, 0, 0);
}

// ---- robust mask decoding ----
__device__ __forceinline__ unsigned mask_code(const void* m) {
    unsigned u0 = ((const unsigned*)m)[0];
    unsigned u1 = ((const unsigned*)m)[1];
    if (u0 == 0x3F803F80u) return 2;
    if (u0 == 0x3F800000u) return 3;
    if (u0 == 0x01010101u) return 4;
    if (u0 == 0x00010001u) return 5;
    if (u0 == 1u && u1 == 0u) return 1;
    return 0;
}
__device__ __forceinline__ float mask_at(const void* m, unsigned code, int i) {
    switch (code) {
        case 1: return (float)((const long long*)m)[i];
        case 2: { unsigned u = (unsigned)((const ushort_t*)m)[i] << 16;
                  return __builtin_bit_cast(float, u); }
        case 3: return ((const float*)m)[i];
        case 4: return (float)((const signed char*)m)[i];
        case 5: return (float)((const short*)m)[i];
        default: return (float)((const int*)m)[i];
    }
}

// ---- prep: convWt (1536 blk) | sincos (64 blk) — convA fused into gemm1 ----
__global__ void k_prep(const float* __restrict__ W) {
    __shared__ ushort_t tile[32][33];
    int bid = blockIdx.x;
    int tid = threadIdx.x;
    if (bid < 1536) {
        int bx = bid % 48;
        int by = bid / 48;
        int tx = tid & 31, ty = tid >> 5;
        #pragma unroll
        for (int i = 0; i < 4; ++i) {
            int k = by * 32 + ty + i * 8;
            int n = bx * 32 + tx;
            tile[ty + i * 8][tx] = f2bf(W[(size_t)k * NOUT + n]);
        }
        __syncthreads();
        #pragma unroll
        for (int i = 0; i < 4; ++i) {
            int n = bx * 32 + ty + i * 8;
            int k = by * 32 + tx;
            g_Wt[(size_t)n * HIDDEN + k] = tile[tx][ty + i * 8];
        }
    } else {
        int i = (bid - 1536) * 256 + tid;         // 0 .. 16383
        int s = i >> 5, f = i & 31;
        float inv = powf(10000.0f, -(float)(2 * f) / 64.0f);
        float ang = (float)s * inv;
        g_tab[2 * i]     = sinf(ang);
        g_tab[2 * i + 1] = cosf(ang);
    }
}

// ---- GEMM1: 64x128, BK=64, A reg-staged fp32->bf16 (fused conv, T14 split),
//      B via gload_lds; XOR-swizzled LDS; dbuf; XCD swizzle ----
__global__ void __launch_bounds__(256) k_gemm1(const float* __restrict__ A,
                                               const float* __restrict__ bias) {
    __shared__ __align__(16) ushort_t sA[2][64 * 64];    // 8 KB each
    __shared__ __align__(16) ushort_t sB[2][128 * 64];   // 16 KB each
    int tid = threadIdx.x;
    int lane = tid & 63, wid = tid >> 6;
    int wm = wid >> 1, wn = wid & 1;
    // bijective XCD swizzle: 768 = 8 XCDs x 96
    int bid = (blockIdx.x & 7) * 96 + (blockIdx.x >> 3);
    int bm = (bid & 63) * 64;                     // 64 m-tiles
    int bn = (bid >> 6) * 128;                    // 12 n-tiles

    // A reg-staging: thread t covers row = t>>2, fp32 elems (t&3)*16 .. +15
    int arow = tid >> 2, aj = tid & 3;
    const float* Ap = A + (size_t)(bm + arow) * HIDDEN + aj * 16;
    float4_ fa[4];
    auto loadA = [&](int ks) {
        #pragma unroll
        for (int q = 0; q < 4; ++q) fa[q] = *(const float4_*)(Ap + ks * 64 + q * 4);
    };
    auto writeA = [&](int bi) {
        u16x8 pk0, pk1;
        #pragma unroll
        for (int j = 0; j < 4; ++j) { pk0[j] = f2bf(fa[0][j]); pk0[j+4] = f2bf(fa[1][j]); }
        #pragma unroll
        for (int j = 0; j < 4; ++j) { pk1[j] = f2bf(fa[2][j]); pk1[j+4] = f2bf(fa[3][j]); }
        int c0 = aj * 2;
        *(u16x8*)(sA[bi] + arow * 64 + ((c0     ^ (arow & 7)) * 8)) = pk0;
        *(u16x8*)(sA[bi] + arow * 64 + (((c0+1) ^ (arow & 7)) * 8)) = pk1;
    };
    // B: gload_lds, LDS linear, source chunk pre-swizzled
    auto stageB = [&](int bi, int ks) {
        #pragma unroll
        for (int i = 0; i < 4; ++i) {             // 128 rows x 8 chunks = 1024
            int c = tid + i * 256;
            int row = c >> 3, ch = (c & 7) ^ (row & 7);
            gload16(g_Wt + (size_t)(bn + row) * HIDDEN + ks * 64 + ch * 8,
                    sB[bi] + (size_t)c * 8);
        }
    };

    float4_ acc[2][4] = {};
    const int NT = HIDDEN / 64;                   // 16 iters
    loadA(0);
    writeA(0);
    stageB(0, 0);
    __syncthreads();
    int cur = 0;
    for (int ks = 0; ks < NT; ++ks) {
        if (ks + 1 < NT) {
            loadA(ks + 1);                        // fp32 loads in flight over MFMAs
            stageB(cur ^ 1, ks + 1);
        }
        #pragma unroll
        for (int kk = 0; kk < 2; ++kk) {
            short8 af[2], bfv[4];
            int c0 = kk * 4 + (lane >> 4);        // logical chunk 0..7
            #pragma unroll
            for (int mf = 0; mf < 2; ++mf) {
                int r = wm * 32 + mf * 16 + (lane & 15);
                af[mf] = *(const short8*)(sA[cur] + r * 64 + ((c0 ^ (r & 7)) * 8));
            }
            #pragma unroll
            for (int nf = 0; nf < 4; ++nf) {
                int r = wn * 64 + nf * 16 + (lane & 15);
                bfv[nf] = *(const short8*)(sB[cur] + r * 64 + ((c0 ^ (r & 7)) * 8));
            }
            #pragma unroll
            for (int mf = 0; mf < 2; ++mf)
                #pragma unroll
                for (int nf = 0; nf < 4; ++nf)
                    acc[mf][nf] = __builtin_amdgcn_mfma_f32_16x16x32_bf16(af[mf], bfv[nf], acc[mf][nf], 0, 0, 0);
        }
        if (ks + 1 < NT) writeA(cur ^ 1);         // convert+write after MFMAs
        __syncthreads();
        cur ^= 1;
    }

    // Epilogue (validated map: N=col=lane&15, M=row=(lane>>4)*4+reg); RoPE via lane^1.
    #pragma unroll
    for (int nf = 0; nf < 4; ++nf) {
        int gn = bn + wn * 64 + nf * 16 + (lane & 15);
        float bv = bias[gn];
        int head = gn >> 7;
        int isk  = (gn >> 6) & 1;
        int d0 = gn & 63;
        int fi = d0 >> 1;
        float sgn = (gn & 1) ? 1.0f : -1.0f;
        ushort_t* dst = isk ? g_K : g_Q;
        #pragma unroll
        for (int mf = 0; mf < 2; ++mf) {
            int gm0 = bm + wm * 32 + mf * 16 + ((lane >> 4) * 4);
            #pragma unroll
            for (int r = 0; r < 4; ++r) {
                int gm = gm0 + r;
                int s = gm & (SEQLEN - 1);
                int b = gm >> 9;
                float v = acc[mf][nf][r] + bv;
                float p = __shfl_xor(v, 1, 64);
                const float* tc = g_tab + 2 * (s * 32 + fi);
                float sn = tc[0], cs = tc[1];
                float y = v * cs + sgn * p * sn;
                size_t o = (((size_t)(b * HEADS + head)) * SEQLEN + s) * HEAD_SIZE + d0;
                dst[o] = f2bf(y);
            }
        }
    }
}

// ---- GEMM2: XCD-swizzled blocks, XOR-swizzled LDS, fused penalty + mask ----
__global__ void __launch_bounds__(256) k_gemm2(const void* __restrict__ mask,
                                               float* __restrict__ out) {
    __shared__ __align__(16) ushort_t sQ[128 * 64];
    __shared__ __align__(16) ushort_t sK[128 * 64];
    __shared__ float sMr[128], sMc[128];
    int tid = threadIdx.x;
    int lane = tid & 63, wid = tid >> 6;
    // bijective XCD swizzle: 1536 blocks = 8 XCDs x 192
    int blk = (blockIdx.x & 7) * 192 + (blockIdx.x >> 3);
    int bh = blk >> 4;
    int t = blk & 15;
    int mt = t >> 2, nt = t & 3;
    int b = bh / HEADS;
    bool writeMask = (bh - b * HEADS) == 0;

    const ushort_t* Qb = g_Q + ((size_t)bh * SEQLEN + mt * 128) * HEAD_SIZE;
    const ushort_t* Kb = g_K + ((size_t)bh * SEQLEN + nt * 128) * HEAD_SIZE;
    #pragma unroll
    for (int i = 0; i < 4; ++i) {
        int c = tid + i * 256;
        int row = c >> 3, ch = (c & 7) ^ (row & 7);
        gload16(Qb + (size_t)row * 64 + ch * 8, sQ + (size_t)c * 8);
        gload16(Kb + (size_t)row * 64 + ch * 8, sK + (size_t)c * 8);
    }
    unsigned mcode = mask_code(mask);
    if (tid < 128)      sMr[tid]       = mask_at(mask, mcode, b * SEQLEN + mt * 128 + tid);
    else                sMc[tid - 128] = mask_at(mask, mcode, b * SEQLEN + nt * 128 + (tid - 128));
    __syncthreads();

    int wm = wid >> 1, wn = wid & 1;
    float4_ acc[4][4] = {};
    #pragma unroll
    for (int kk = 0; kk < 2; ++kk) {
        short8 af[4], bfv[4];
        int c0 = kk * 4 + (lane >> 4);
        #pragma unroll
        for (int mf = 0; mf < 4; ++mf) {
            int r = wm * 64 + mf * 16 + (lane & 15);
            af[mf] = *(const short8*)(sQ + r * 64 + ((c0 ^ (r & 7)) * 8));
        }
        #pragma unroll
        for (int nf = 0; nf < 4; ++nf) {
            int r = wn * 64 + nf * 16 + (lane & 15);
            bfv[nf] = *(const short8*)(sK + r * 64 + ((c0 ^ (r & 7)) * 8));
        }
        #pragma unroll
        for (int mf = 0; mf < 4; ++mf)
            #pragma unroll
            for (int nf = 0; nf < 4; ++nf)
                acc[mf][nf] = __builtin_amdgcn_mfma_f32_16x16x32_bf16(af[mf], bfv[nf], acc[mf][nf], 0, 0, 0);
    }

    size_t obase = (size_t)bh * SEQLEN * SEQLEN;
    size_t mbase = (size_t)LOGITS_N + (size_t)b * SEQLEN * SEQLEN;
    #pragma unroll
    for (int mf = 0; mf < 4; ++mf) {
        #pragma unroll
        for (int nf = 0; nf < 4; ++nf) {
            int lcol = wn * 64 + nf * 16 + (lane & 15);
            int lrow0 = wm * 64 + mf * 16 + ((lane >> 4) * 4);
            int gn = nt * 128 + lcol;
            float mc = sMc[lcol];
            #pragma unroll
            for (int r = 0; r < 4; ++r) {
                int lrow = lrow0 + r;
                int gm = mt * 128 + lrow;
                float padv = 1.0f - sMr[lrow] * mc;
                bool tl = gn < gm;
                float v = (acc[mf][nf][r] - padv * INF_ - (tl ? INF_ : 0.0f)) * 0.125f;
                size_t off = (size_t)gm * SEQLEN + gn;
                out[obase + off] = v;
                if (writeMask)
                    out[mbase + off] = (padv > 0.0f || tl) ? 1.0f : 0.0f;
            }
        }
    }
}

extern "C" void kernel_launch(void* const* d_in, const int* in_sizes, int n_in,
                              void* d_out, int out_size, void* d_ws, size_t ws_size,
                              hipStream_t stream) {
    const float* inp = nullptr; const float* W = nullptr;
    const float* bias = nullptr; const void* mask = nullptr;
    for (int i = 0; i < n_in; ++i) {
        switch (in_sizes[i]) {
            case MROWS * HIDDEN:  inp  = (const float*)d_in[i]; break;
            case HIDDEN * NOUT:   W    = (const float*)d_in[i]; break;
            case NOUT:            bias = (const float*)d_in[i]; break;
            case BATCH * SEQLEN:  mask = d_in[i]; break;
        }
    }
    if (!inp || !W || !bias || !mask) {
        inp  = (const float*)d_in[0];
        W    = (const float*)d_in[1];
        bias = (const float*)d_in[2];
        mask = d_in[3];
    }
    float* out = (float*)d_out;                    // fp32 output buffer
    (void)d_ws; (void)ws_size;

    k_prep<<<1600, 256, 0, stream>>>(W);
    k_gemm1<<<768, 256, 0, stream>>>(inp, bias);
    k_gemm2<<<16 * BH, 256, 0, stream>>>(mask, out);
}

// Round 20
// 59.547 us; speedup vs baseline: 1.0873x; 1.0873x over previous
//
#include <hip/hip_runtime.h>
#include <stdint.h>

typedef unsigned short ushort_t;
typedef short short8 __attribute__((ext_vector_type(8)));
typedef float float4_ __attribute__((ext_vector_type(4)));
typedef unsigned short u16x8 __attribute__((ext_vector_type(8)));

#define INF_ 10000.0f
#define BATCH 8
#define SEQLEN 512
#define HIDDEN 1024
#define HEADS 12
#define HEAD_SIZE 64
#define NOUT 1536          // HEADS * 2 * HEAD_SIZE
#define MROWS 4096         // BATCH * SEQLEN
#define BH 96              // BATCH * HEADS
#define LOGITS_N 25165824  // (8,12,512,512)
#define MASK_N   2097152   // (8,1,512,512)

// ---- module-scope device scratch ----
__device__ __align__(16) ushort_t g_A [(size_t)MROWS * HIDDEN];           // 8 MB bf16
__device__ __align__(16) ushort_t g_Wt[(size_t)NOUT * HIDDEN];            // 3 MB bf16
__device__ __align__(16) ushort_t g_Q[(size_t)BH * SEQLEN * HEAD_SIZE];   // 6 MB
__device__ __align__(16) ushort_t g_K[(size_t)BH * SEQLEN * HEAD_SIZE];   // 6 MB
__device__ __align__(16) float    g_tab[SEQLEN * 32 * 2];                 // 128 KB

__device__ __forceinline__ ushort_t f2bf(float f) {
    unsigned u = __builtin_bit_cast(unsigned, f);
    unsigned r = u + 0x7FFFu + ((u >> 16) & 1u);
    return (ushort_t)(r >> 16);
}

// async global->LDS 16B (LDS dest = wave-uniform base + lane*16, linear)
__device__ __forceinline__ void gload16(const ushort_t* g, ushort_t* l) {
    __builtin_amdgcn_global_load_lds(
        (const __attribute__((address_space(1))) void*)g,
        (__attribute__((address_space(3))) void*)l, 16, 0, 0);
}

// ---- robust mask decoding ----
__device__ __forceinline__ unsigned mask_code(const void* m) {
    unsigned u0 = ((const unsigned*)m)[0];
    unsigned u1 = ((const unsigned*)m)[1];
    if (u0 == 0x3F803F80u) return 2;
    if (u0 == 0x3F800000u) return 3;
    if (u0 == 0x01010101u) return 4;
    if (u0 == 0x00010001u) return 5;
    if (u0 == 1u && u1 == 0u) return 1;
    return 0;
}
__device__ __forceinline__ float mask_at(const void* m, unsigned code, int i) {
    switch (code) {
        case 1: return (float)((const long long*)m)[i];
        case 2: { unsigned u = (unsigned)((const ushort_t*)m)[i] << 16;
                  return __builtin_bit_cast(float, u); }
        case 3: return ((const float*)m)[i];
        case 4: return (float)((const signed char*)m)[i];
        case 5: return (float)((const short*)m)[i];
        default: return (float)((const int*)m)[i];
    }
}

// ---- fused prep: convA (2048 blk) | convWt (1536 blk) | sincos (64 blk) ----
__global__ void k_prep(const float* __restrict__ A, const float* __restrict__ W) {
    __shared__ ushort_t tile[32][33];
    int bid = blockIdx.x;
    int tid = threadIdx.x;
    if (bid < 2048) {
        int i = bid * 256 + tid;
        const float4_* p = (const float4_*)(A + (size_t)i * 8);
        float4_ v0 = p[0], v1 = p[1];
        u16x8 o;
        #pragma unroll
        for (int j = 0; j < 4; ++j) { o[j] = f2bf(v0[j]); o[j + 4] = f2bf(v1[j]); }
        *(u16x8*)(g_A + (size_t)i * 8) = o;
    } else if (bid < 2048 + 1536) {
        int bb = bid - 2048;
        int bx = bb % 48;
        int by = bb / 48;
        int tx = tid & 31, ty = tid >> 5;
        #pragma unroll
        for (int i = 0; i < 4; ++i) {
            int k = by * 32 + ty + i * 8;
            int n = bx * 32 + tx;
            tile[ty + i * 8][tx] = f2bf(W[(size_t)k * NOUT + n]);
        }
        __syncthreads();
        #pragma unroll
        for (int i = 0; i < 4; ++i) {
            int n = bx * 32 + ty + i * 8;
            int k = by * 32 + tx;
            g_Wt[(size_t)n * HIDDEN + k] = tile[tx][ty + i * 8];
        }
    } else {
        int i = (bid - 3584) * 256 + tid;
        int s = i >> 5, f = i & 31;
        float inv = powf(10000.0f, -(float)(2 * f) / 64.0f);
        float ang = (float)s * inv;
        g_tab[2 * i]     = sinf(ang);
        g_tab[2 * i + 1] = cosf(ang);
    }
}

// ---- GEMM1: 64x128 tile, BK=64, XOR-swizzled LDS, gload_lds, dbuf ----
__global__ void __launch_bounds__(256) k_gemm1(const float* __restrict__ bias) {
    __shared__ __align__(16) ushort_t sA[2][64 * 64];    // 8 KB each
    __shared__ __align__(16) ushort_t sB[2][128 * 64];   // 16 KB each
    int tid = threadIdx.x;
    int lane = tid & 63, wid = tid >> 6;
    int wm = wid >> 1, wn = wid & 1;
    int bm = (blockIdx.x & 63) * 64;              // 64 m-tiles
    int bn = (blockIdx.x >> 6) * 128;             // 12 n-tiles

    // stage: LDS dest linear (slot c -> 16B), global source chunk = (c&7)^(row&7)
    auto stage = [&](int bi, int ks) {
        #pragma unroll
        for (int i = 0; i < 2; ++i) {             // A: 64 rows x 8 chunks = 512
            int c = tid + i * 256;
            int row = c >> 3, ch = (c & 7) ^ (row & 7);
            gload16(g_A + (size_t)(bm + row) * HIDDEN + ks * 64 + ch * 8,
                    sA[bi] + (size_t)c * 8);
        }
        #pragma unroll
        for (int i = 0; i < 4; ++i) {             // B: 128 rows x 8 chunks = 1024
            int c = tid + i * 256;
            int row = c >> 3, ch = (c & 7) ^ (row & 7);
            gload16(g_Wt + (size_t)(bn + row) * HIDDEN + ks * 64 + ch * 8,
                    sB[bi] + (size_t)c * 8);
        }
    };

    float4_ acc[2][4] = {};
    const int NT = HIDDEN / 64;                   // 16 iters
    stage(0, 0);
    __syncthreads();
    int cur = 0;
    for (int ks = 0; ks < NT; ++ks) {
        if (ks + 1 < NT) stage(cur ^ 1, ks + 1);
        #pragma unroll
        for (int kk = 0; kk < 2; ++kk) {
            short8 af[2], bfv[4];
            int c0 = kk * 4 + (lane >> 4);        // logical chunk 0..7
            #pragma unroll
            for (int mf = 0; mf < 2; ++mf) {
                int r = wm * 32 + mf * 16 + (lane & 15);
                af[mf] = *(const short8*)(sA[cur] + r * 64 + ((c0 ^ (r & 7)) * 8));
            }
            #pragma unroll
            for (int nf = 0; nf < 4; ++nf) {
                int r = wn * 64 + nf * 16 + (lane & 15);
                bfv[nf] = *(const short8*)(sB[cur] + r * 64 + ((c0 ^ (r & 7)) * 8));
            }
            #pragma unroll
            for (int mf = 0; mf < 2; ++mf)
                #pragma unroll
                for (int nf = 0; nf < 4; ++nf)
                    acc[mf][nf] = __builtin_amdgcn_mfma_f32_16x16x32_bf16(af[mf], bfv[nf], acc[mf][nf], 0, 0, 0);
        }
        __syncthreads();
        cur ^= 1;
    }

    // Epilogue (validated map: N=col=lane&15, M=row=(lane>>4)*4+reg); RoPE via lane^1.
    #pragma unroll
    for (int nf = 0; nf < 4; ++nf) {
        int gn = bn + wn * 64 + nf * 16 + (lane & 15);
        float bv = bias[gn];
        int head = gn >> 7;
        int isk  = (gn >> 6) & 1;
        int d0 = gn & 63;
        int fi = d0 >> 1;
        float sgn = (gn & 1) ? 1.0f : -1.0f;
        ushort_t* dst = isk ? g_K : g_Q;
        #pragma unroll
        for (int mf = 0; mf < 2; ++mf) {
            int gm0 = bm + wm * 32 + mf * 16 + ((lane >> 4) * 4);
            #pragma unroll
            for (int r = 0; r < 4; ++r) {
                int gm = gm0 + r;
                int s = gm & (SEQLEN - 1);
                int b = gm >> 9;
                float v = acc[mf][nf][r] + bv;
                float p = __shfl_xor(v, 1, 64);
                const float* tc = g_tab + 2 * (s * 32 + fi);
                float sn = tc[0], cs = tc[1];
                float y = v * cs + sgn * p * sn;
                size_t o = (((size_t)(b * HEADS + head)) * SEQLEN + s) * HEAD_SIZE + d0;
                dst[o] = f2bf(y);
            }
        }
    }
}

// ---- GEMM2: XCD-swizzled blocks, XOR-swizzled LDS, fused penalty + mask ----
__global__ void __launch_bounds__(256) k_gemm2(const void* __restrict__ mask,
                                               float* __restrict__ out) {
    __shared__ __align__(16) ushort_t sQ[128 * 64];
    __shared__ __align__(16) ushort_t sK[128 * 64];
    __shared__ float sMr[128], sMc[128];
    int tid = threadIdx.x;
    int lane = tid & 63, wid = tid >> 6;
    // bijective XCD swizzle: 1536 blocks = 8 XCDs x 192
    int blk = (blockIdx.x & 7) * 192 + (blockIdx.x >> 3);
    int bh = blk >> 4;
    int t = blk & 15;
    int mt = t >> 2, nt = t & 3;
    int b = bh / HEADS;
    bool writeMask = (bh - b * HEADS) == 0;

    const ushort_t* Qb = g_Q + ((size_t)bh * SEQLEN + mt * 128) * HEAD_SIZE;
    const ushort_t* Kb = g_K + ((size_t)bh * SEQLEN + nt * 128) * HEAD_SIZE;
    #pragma unroll
    for (int i = 0; i < 4; ++i) {
        int c = tid + i * 256;
        int row = c >> 3, ch = (c & 7) ^ (row & 7);
        gload16(Qb + (size_t)row * 64 + ch * 8, sQ + (size_t)c * 8);
        gload16(Kb + (size_t)row * 64 + ch * 8, sK + (size_t)c * 8);
    }
    unsigned mcode = mask_code(mask);
    if (tid < 128)      sMr[tid]       = mask_at(mask, mcode, b * SEQLEN + mt * 128 + tid);
    else                sMc[tid - 128] = mask_at(mask, mcode, b * SEQLEN + nt * 128 + (tid - 128));
    __syncthreads();

    int wm = wid >> 1, wn = wid & 1;
    float4_ acc[4][4] = {};
    #pragma unroll
    for (int kk = 0; kk < 2; ++kk) {
        short8 af[4], bfv[4];
        int c0 = kk * 4 + (lane >> 4);
        #pragma unroll
        for (int mf = 0; mf < 4; ++mf) {
            int r = wm * 64 + mf * 16 + (lane & 15);
            af[mf] = *(const short8*)(sQ + r * 64 + ((c0 ^ (r & 7)) * 8));
        }
        #pragma unroll
        for (int nf = 0; nf < 4; ++nf) {
            int r = wn * 64 + nf * 16 + (lane & 15);
            bfv[nf] = *(const short8*)(sK + r * 64 + ((c0 ^ (r & 7)) * 8));
        }
        #pragma unroll
        for (int mf = 0; mf < 4; ++mf)
            #pragma unroll
            for (int nf = 0; nf < 4; ++nf)
                acc[mf][nf] = __builtin_amdgcn_mfma_f32_16x16x32_bf16(af[mf], bfv[nf], acc[mf][nf], 0, 0, 0);
    }

    size_t obase = (size_t)bh * SEQLEN * SEQLEN;
    size_t mbase = (size_t)LOGITS_N + (size_t)b * SEQLEN * SEQLEN;
    #pragma unroll
    for (int mf = 0; mf < 4; ++mf) {
        #pragma unroll
        for (int nf = 0; nf < 4; ++nf) {
            int lcol = wn * 64 + nf * 16 + (lane & 15);
            int lrow0 = wm * 64 + mf * 16 + ((lane >> 4) * 4);
            int gn = nt * 128 + lcol;
            float mc = sMc[lcol];
            #pragma unroll
            for (int r = 0; r < 4; ++r) {
                int lrow = lrow0 + r;
                int gm = mt * 128 + lrow;
                float padv = 1.0f - sMr[lrow] * mc;
                bool tl = gn < gm;
                float v = (acc[mf][nf][r] - padv * INF_ - (tl ? INF_ : 0.0f)) * 0.125f;
                size_t off = (size_t)gm * SEQLEN + gn;
                out[obase + off] = v;
                if (writeMask)
                    out[mbase + off] = (padv > 0.0f || tl) ? 1.0f : 0.0f;
            }
        }
    }
}

extern "C" void kernel_launch(void* const* d_in, const int* in_sizes, int n_in,
                              void* d_out, int out_size, void* d_ws, size_t ws_size,
                              hipStream_t stream) {
    const float* inp = nullptr; const float* W = nullptr;
    const float* bias = nullptr; const void* mask = nullptr;
    for (int i = 0; i < n_in; ++i) {
        switch (in_sizes[i]) {
            case MROWS * HIDDEN:  inp  = (const float*)d_in[i]; break;
            case HIDDEN * NOUT:   W    = (const float*)d_in[i]; break;
            case NOUT:            bias = (const float*)d_in[i]; break;
            case BATCH * SEQLEN:  mask = d_in[i]; break;
        }
    }
    if (!inp || !W || !bias || !mask) {
        inp  = (const float*)d_in[0];
        W    = (const float*)d_in[1];
        bias = (const float*)d_in[2];
        mask = d_in[3];
    }
    float* out = (float*)d_out;                    // fp32 output buffer
    (void)d_ws; (void)ws_size;

    k_prep<<<3648, 256, 0, stream>>>(inp, W);
    k_gemm1<<<768, 256, 0, stream>>>(bias);
    k_gemm2<<<16 * BH, 256, 0, stream>>>(mask, out);
}